// Round 1
// baseline (32479.868 us; speedup 1.0000x reference)
//
#include <hip/hip_runtime.h>

typedef unsigned short u16;
typedef __attribute__((ext_vector_type(8))) short bf16x8;
typedef __attribute__((ext_vector_type(8))) unsigned short u16x8;
typedef __attribute__((ext_vector_type(4))) unsigned short u16x4;
typedef __attribute__((ext_vector_type(4))) float f32x4;

#define DI static __device__ __forceinline__

// ---------------- workspace layout (bytes) ----------------
constexpr size_t OFF_WKQ  = 0;                               // 256x256 f32  (scale*Wk@Wq^T)
constexpr size_t OFF_WVW  = OFF_WKQ  + 256*256*4;            // 256x128 f32  (Wv@W3)
constexpr size_t OFF_WB   = OFF_WVW  + 256*128*4;            // 256 f32      (scale*Wk@bq)
constexpr size_t OFF_BYV  = OFF_WB   + 256*4;                // 128 f32      (b3 + bv@W3)
constexpr size_t OFF_BG   = OFF_BYV  + 128*4;                // 2048 f32     (bih+bhh)
constexpr size_t OFF_W2B  = OFF_BG   + 2048*4;               // 512x256 bf16
constexpr size_t OFF_W1F  = OFF_W2B  + 512*256*2;            // 16*4*64*8 bf16 (frag-swizzled W1)
constexpr size_t OFF_WIHF = OFF_W1F  + 16*4*64*8*2;          // 128*8*64*8 bf16
constexpr size_t OFF_WHHF = OFF_WIHF + 128*8*64*8*2;         // 128*16*64*8 bf16
constexpr size_t OFF_KT   = OFF_WHHF + 128*16*64*8*2;        // 64*1024*256 bf16
constexpr size_t OFF_VW   = OFF_KT   + (size_t)64*1024*256*2;// 64*1024*128 bf16
constexpr size_t OFF_S0   = OFF_VW   + (size_t)64*1024*128*2;// 65536 f32
constexpr size_t OFF_CB   = OFF_S0   + 65536*4;              // 64x512 f32 cell state
constexpr size_t OFF_HF   = OFF_CB   + 64*512*4;             // 64x512 f32 h
constexpr size_t OFF_HFR  = OFF_HF   + 64*512*4;             // 2 x (16*4*64*8) bf16 h frags (ping-pong)
constexpr size_t OFF_SC   = OFF_HFR  + 2*16*4*64*8*2;        // 64x1024 f32 raw scores
constexpr size_t OFF_PART = OFF_SC   + 64*1024*4;            // 64x4x130 f32 (m,S,ctx[128])

DI float bf2f(u16 u){ unsigned int v = ((unsigned int)u) << 16; return __uint_as_float(v); }
DI u16 f2bf(float f){ unsigned int u = __float_as_uint(f); unsigned int r = (u + 0x7FFFu + ((u>>16)&1u)) >> 16; return (u16)r; }
DI float sigm(float x){ return 1.f/(1.f + __expf(-x)); }
DI float tanh_(float x){ return 1.f - 2.f/(__expf(2.f*x) + 1.f); }

// frag slot for an A-operand element [row m][k]: lane=(m&15)|(((k>>3)&3)<<4), i=k&7, ktile=k>>5, mtile=m>>4
DI int fragIdx(int m, int k){ return (((k>>5)*4 + (m>>4))*64 + ((m&15) | (((k>>3)&3)<<4)))*8 + (k&7); }

// ---------------- one-time weight prep ----------------
__global__ __launch_bounds__(256) void kPrep(char* ws,
    const float* W1, const float* Wih, const float* Whh, const float* W2,
    const float* Wq, const float* bq, const float* Wk, const float* bk,
    const float* Wv, const float* bv, const float* W3, const float* b3,
    const float* bih, const float* bhh, const float* c0, const float* h0)
{
  const int wg = blockIdx.x, tid = threadIdx.x;
  if (wg < 64) {                       // Wkq[e][d] = scale * dot(Wk row e, Wq row d)
    float* Wkq = (float*)(ws + OFF_WKQ);
    for (int rr = 0; rr < 4; ++rr) {
      const int e = wg*4 + rr;
      float acc = 0.f;
      for (int d = 0; d < 256; ++d) acc = fmaf(Wk[e*256+d], Wq[tid*256+d], acc);
      Wkq[e*256 + tid] = acc * 0.0625f;
    }
  } else if (wg < 96) {                // Wvw[e][o] = dot(Wv row e, W3 col o)
    float* Wvw = (float*)(ws + OFF_WVW);
    if (tid < 128) {
      for (int rr = 0; rr < 8; ++rr) {
        const int e = (wg-64)*8 + rr;
        float acc = 0.f;
        for (int d = 0; d < 256; ++d) acc = fmaf(Wv[e*256+d], W3[d*128+tid], acc);
        Wvw[e*128 + tid] = acc;
      }
    }
  } else if (wg == 96) {               // wb, byv
    float* wb = (float*)(ws + OFF_WB);
    float acc = 0.f;
    for (int d = 0; d < 256; ++d) acc = fmaf(Wk[tid*256+d], bq[d], acc);
    wb[tid] = acc * 0.0625f;
    if (tid < 128) {
      float* byv = (float*)(ws + OFF_BYV);
      float a2 = b3[tid];
      for (int d = 0; d < 256; ++d) a2 = fmaf(bv[d], W3[d*128+tid], a2);
      byv[tid] = a2;
    }
  } else if (wg == 97) {               // bg = bih + bhh
    float* bg = (float*)(ws + OFF_BG);
    for (int j = tid; j < 2048; j += 256) bg[j] = bih[j] + bhh[j];
  } else if (wg < 106) {               // W2 -> bf16
    u16* W2b = (u16*)(ws + OFF_W2B);
    const int r0 = (wg - 98)*64;
    for (int rr = 0; rr < 64; ++rr) W2b[(r0+rr)*256 + tid] = f2bf(W2[(r0+rr)*256 + tid]);
  } else if (wg < 122) {               // W1 frag swizzle (B-operand): n natural order
    u16* W1f = (u16*)(ws + OFF_W1F);
    const int nt2 = wg - 106;
    for (int idx = tid; idx < 4*512; idx += 256) {
      const int kt2 = idx >> 9, rem = idx & 511, lane = rem >> 3, i = rem & 7;
      const int k = kt2*32 + (lane>>4)*8 + i, n = nt2*16 + (lane&15);
      W1f[((nt2*4+kt2)*64+lane)*8+i] = f2bf(W1[k*256+n]);
    }
  } else if (wg < 250) {               // Wih frag swizzle, gate-interleaved col permutation
    u16* Wihf = (u16*)(ws + OFF_WIHF);
    const int nt = wg - 122;
    for (int idx = tid; idx < 8*512; idx += 256) {
      const int kt = idx >> 9, rem = idx & 511, lane = rem >> 3, i = rem & 7;
      const int k = kt*32 + (lane>>4)*8 + i, r = lane & 15;
      const int gcol = (r>>2)*512 + nt*4 + (r&3);   // r: 0..3=i,4..7=f,8..11=g,12..15=o for j=nt*4+(r&3)
      Wihf[((nt*8+kt)*64+lane)*8+i] = f2bf(Wih[k*2048 + gcol]);
    }
  } else if (wg < 378) {               // Whh frag swizzle
    u16* Whhf = (u16*)(ws + OFF_WHHF);
    const int nt = wg - 250;
    for (int idx = tid; idx < 16*512; idx += 256) {
      const int kt = idx >> 9, rem = idx & 511, lane = rem >> 3, i = rem & 7;
      const int k = kt*32 + (lane>>4)*8 + i, r = lane & 15;
      const int gcol = (r>>2)*512 + nt*4 + (r&3);
      Whhf[((nt*16+kt)*64+lane)*8+i] = f2bf(Whh[k*2048 + gcol]);
    }
  } else if (wg < 410) {               // state init: c0 -> cbuf, h0 -> hfrag[0]
    float* cb = (float*)(ws + OFF_CB);
    u16* hfr0 = (u16*)(ws + OFF_HFR);
    const int base = (wg - 378)*1024;
    for (int ii = tid; ii < 1024; ii += 256) {
      const int idx = base + ii, b = idx >> 9, j = idx & 511;
      cb[idx] = c0[idx];
      hfr0[fragIdx(b, j)] = f2bf(h0[idx]);
    }
  }
}

// ---------------- precompute kt, vw, s0 ----------------
__global__ __launch_bounds__(256) void kKTVW(char* __restrict__ ws, const float* __restrict__ hid_r)
{
  const int wg = blockIdx.x, tid = threadIdx.x;
  __shared__ float lh[256*36];  // [e][r], padded to 36 for banks + float4 align
  const float* Wkq = (const float*)(ws + OFF_WKQ);
  const float* Wvw = (const float*)(ws + OFF_WVW);
  const float* wb  = (const float*)(ws + OFF_WB);
  u16* kt = (u16*)(ws + OFF_KT);
  u16* vw = (u16*)(ws + OFF_VW);
  float* s0 = (float*)(ws + OFF_S0);
  const size_t r0 = (size_t)wg * 32;
  for (int idx = tid; idx < 32*256; idx += 256) {
    const int e = idx & 255, r = idx >> 8;
    lh[e*36 + r] = hid_r[(r0 + r)*256 + e];
  }
  __syncthreads();
  float acc[32];
  #pragma unroll
  for (int r = 0; r < 32; ++r) acc[r] = 0.f;
  for (int e = 0; e < 256; ++e) {
    const float wv = Wkq[e*256 + tid];
    #pragma unroll
    for (int r4 = 0; r4 < 8; ++r4) {
      const float4 l4 = *(const float4*)&lh[e*36 + r4*4];
      acc[r4*4+0] = fmaf(l4.x, wv, acc[r4*4+0]);
      acc[r4*4+1] = fmaf(l4.y, wv, acc[r4*4+1]);
      acc[r4*4+2] = fmaf(l4.z, wv, acc[r4*4+2]);
      acc[r4*4+3] = fmaf(l4.w, wv, acc[r4*4+3]);
    }
  }
  for (int r = 0; r < 32; ++r) kt[(r0 + r)*256 + tid] = f2bf(acc[r]);
  if (tid < 128) {
    #pragma unroll
    for (int r = 0; r < 32; ++r) acc[r] = 0.f;
    for (int e = 0; e < 256; ++e) {
      const float wv = Wvw[e*128 + tid];
      #pragma unroll
      for (int r4 = 0; r4 < 8; ++r4) {
        const float4 l4 = *(const float4*)&lh[e*36 + r4*4];
        acc[r4*4+0] = fmaf(l4.x, wv, acc[r4*4+0]);
        acc[r4*4+1] = fmaf(l4.y, wv, acc[r4*4+1]);
        acc[r4*4+2] = fmaf(l4.z, wv, acc[r4*4+2]);
        acc[r4*4+3] = fmaf(l4.w, wv, acc[r4*4+3]);
      }
    }
    for (int r = 0; r < 32; ++r) vw[(r0 + r)*128 + tid] = f2bf(acc[r]);
  } else if (tid < 160) {
    const int r = tid - 128;
    float a3 = 0.f;
    for (int e = 0; e < 256; ++e) a3 = fmaf(lh[e*36 + r], wb[e], a3);
    s0[r0 + r] = a3;
  }
}

// ---------------- phase A: combine->y->a->gates->h,c  +  attn/output writers ----------------
__global__ __launch_bounds__(512) void kA(char* __restrict__ ws, const float* __restrict__ init_in,
    const float* __restrict__ in_mask, const float* __restrict__ b1, float* __restrict__ dout, int s)
{
  const int wg = blockIdx.x, tid = threadIdx.x;
  float* part = (float*)(ws + OFF_PART);
  float* scores = (float*)(ws + OFF_SC);

  if (wg >= 128) {  // ---- writers for step s-1 ----
    if (s == 0) return;
    const int b = (wg - 128) >> 1, half = (wg - 128) & 1;
    float pm[4], pS[4], m = -1e30f;
    #pragma unroll
    for (int c = 0; c < 4; ++c) { pm[c] = part[(b*4+c)*130]; pS[c] = part[(b*4+c)*130+1]; m = fmaxf(m, pm[c]); }
    float Sv = 0.f;
    #pragma unroll
    for (int c = 0; c < 4; ++c) Sv += pS[c] * __expf(pm[c]-m);
    const float inv = 1.f / Sv;
    const int t = s - 1;
    const int l = half*512 + tid;
    float* attn = dout + (size_t)64*1024*128;
    attn[((size_t)b*1024 + t)*1024 + l] = __expf(scores[b*1024 + l] - m) * inv;
    if (half == 0 && tid < 128) {
      const float* byv = (const float*)(ws + OFF_BYV);
      float a2 = 0.f;
      #pragma unroll
      for (int c = 0; c < 4; ++c) a2 += __expf(pm[c]-m) * part[(b*4+c)*130+2+tid];
      const float y = fmaxf(a2*inv + byv[tid], 0.f);
      dout[((size_t)b*1024 + t)*128 + tid] = y * in_mask[b*1024 + t];
    }
    return;
  }

  // ---- gates WG (nt = wg owns h columns j = wg*4..wg*4+3) ----
  __shared__ u16 yfrag[4*4*64*8];
  __shared__ u16 afrag[8*4*64*8];
  __shared__ float lfac[64*4];
  __shared__ float gmerge[4*64*4];
  __shared__ float gtile[64*16];
  const float* byv = (const float*)(ws + OFF_BYV);

  // stage 1: y -> yfrag (bf16 A-operand layout)
  if (s == 0) {
    for (int idx = tid; idx < 64*128; idx += 512) {
      const int b = idx >> 7, d0 = idx & 127;
      yfrag[fragIdx(b, d0)] = f2bf(init_in[b*128 + d0]);
    }
  } else {
    if (tid < 64) {
      const int b = tid;
      float pm[4], m = -1e30f;
      #pragma unroll
      for (int c = 0; c < 4; ++c) { pm[c] = part[(b*4+c)*130]; m = fmaxf(m, pm[c]); }
      float Sv = 0.f, pf[4];
      #pragma unroll
      for (int c = 0; c < 4; ++c) { pf[c] = __expf(pm[c]-m); Sv += part[(b*4+c)*130+1]*pf[c]; }
      const float inv = 1.f/Sv;
      #pragma unroll
      for (int c = 0; c < 4; ++c) lfac[b*4+c] = pf[c]*inv;
    }
    __syncthreads();
    for (int idx = tid; idx < 64*128; idx += 512) {
      const int b = idx >> 7, d0 = idx & 127;
      float a2 = byv[d0];
      #pragma unroll
      for (int c = 0; c < 4; ++c) a2 += lfac[b*4+c]*part[(b*4+c)*130+2+d0];
      yfrag[fragIdx(b, d0)] = f2bf(fmaxf(a2, 0.f));
    }
  }
  __syncthreads();

  const int w = tid >> 6, lane = tid & 63;
  // stage 2: a = relu(y@W1 + b1), all 8 waves, redundant full 64x256 per WG
  {
    const u16* W1f = (const u16*)(ws + OFF_W1F);
    const int mt = w & 3;
    for (int nb = 0; nb < 8; ++nb) {
      const int nt2 = (w>>2)*8 + nb;
      f32x4 acc = {0.f,0.f,0.f,0.f};
      #pragma unroll
      for (int kt2 = 0; kt2 < 4; ++kt2) {
        bf16x8 av = *(const bf16x8*)&yfrag[((kt2*4+mt)*64+lane)*8];
        bf16x8 bv = *(const bf16x8*)&W1f[((nt2*4+kt2)*64+lane)*8];
        acc = __builtin_amdgcn_mfma_f32_16x16x32_bf16(av, bv, acc, 0, 0, 0);
      }
      const int col = nt2*16 + (lane&15);
      const float bb = b1[col];
      #pragma unroll
      for (int i = 0; i < 4; ++i) {
        const int b = mt*16 + (lane>>4)*4 + i;
        afrag[fragIdx(b, col)] = f2bf(fmaxf(acc[i] + bb, 0.f));
      }
    }
  }
  __syncthreads();
  // stage 3: gates tile 64x16 = a@Wih + h@Whh + bg, K split across wave pairs
  {
    const u16* Wihf = (const u16*)(ws + OFF_WIHF);
    const u16* Whhf = (const u16*)(ws + OFF_WHHF);
    const u16* hfr = (const u16*)(ws + OFF_HFR) + (size_t)(s & 1)*(16*4*64*8);
    const int nt = wg, mt = w & 3;
    f32x4 acc = {0.f,0.f,0.f,0.f};
    if (w < 4) {
      for (int kt = 0; kt < 8; ++kt) {
        bf16x8 av = *(const bf16x8*)&afrag[((kt*4+mt)*64+lane)*8];
        bf16x8 bv = *(const bf16x8*)&Wihf[((nt*8+kt)*64+lane)*8];
        acc = __builtin_amdgcn_mfma_f32_16x16x32_bf16(av, bv, acc, 0, 0, 0);
      }
      for (int kt = 0; kt < 4; ++kt) {
        bf16x8 av = *(const bf16x8*)&hfr[((kt*4+mt)*64+lane)*8];
        bf16x8 bv = *(const bf16x8*)&Whhf[((nt*16+kt)*64+lane)*8];
        acc = __builtin_amdgcn_mfma_f32_16x16x32_bf16(av, bv, acc, 0, 0, 0);
      }
    } else {
      for (int kt = 4; kt < 16; ++kt) {
        bf16x8 av = *(const bf16x8*)&hfr[((kt*4+mt)*64+lane)*8];
        bf16x8 bv = *(const bf16x8*)&Whhf[((nt*16+kt)*64+lane)*8];
        acc = __builtin_amdgcn_mfma_f32_16x16x32_bf16(av, bv, acc, 0, 0, 0);
      }
      #pragma unroll
      for (int i = 0; i < 4; ++i) gmerge[(mt*64+lane)*4+i] = acc[i];
    }
    __syncthreads();
    if (w < 4) {
      const float* bg = (const float*)(ws + OFF_BG);
      const int r = lane & 15;
      const float bb = bg[(r>>2)*512 + nt*4 + (r&3)];
      #pragma unroll
      for (int i = 0; i < 4; ++i) {
        const int b = mt*16 + (lane>>4)*4 + i;
        gtile[b*16 + r] = acc[i] + gmerge[(mt*64+lane)*4+i] + bb;
      }
    }
  }
  __syncthreads();
  // stage 4: h,c pointwise for this WG's 4 j columns
  if (tid < 256) {
    const int b = tid >> 2, jj = tid & 3;
    const int j = wg*4 + jj;
    const float ig = gtile[b*16 + jj],     fg = gtile[b*16 + 4 + jj];
    const float gg = gtile[b*16 + 8 + jj], og = gtile[b*16 + 12 + jj];
    float* cb = (float*)(ws + OFF_CB);
    float* hf = (float*)(ws + OFF_HF);
    u16* hfw = (u16*)(ws + OFF_HFR) + (size_t)((s & 1) ^ 1)*(16*4*64*8);
    const float cold = cb[b*512 + j];
    const float cnew = sigm(fg)*cold + sigm(ig)*tanh_(gg);
    const float hnew = sigm(og)*tanh_(cnew);
    cb[b*512 + j] = cnew;
    hf[b*512 + j] = hnew;
    hfw[fragIdx(b, j)] = f2bf(hnew);
  }
}

// ---------------- phase B: dx + flash attention chunk ----------------
__global__ __launch_bounds__(1024) void kB(char* __restrict__ ws, const float* __restrict__ in_mask,
                                           const float* __restrict__ b2, int s)
{
  const int wg = blockIdx.x, tid = threadIdx.x;
  const int b = wg >> 2, ch = wg & 3;
  __shared__ float red[4*256];
  __shared__ float dxl[256];
  __shared__ float mrg[32*132];
  const float* hf = (const float*)(ws + OFF_HF);
  const u16* W2b = (const u16*)(ws + OFF_W2B);
  (void)s;
  {  // dx = relu(h[b]@W2 + b2), redundant per chunk-WG
    const int n = tid & 255, q = tid >> 8;
    const float* hb = hf + b*512;
    float acc = 0.f;
    #pragma unroll 4
    for (int k = q*128; k < q*128 + 128; ++k)
      acc = fmaf(hb[k], bf2f(W2b[k*256 + n]), acc);
    red[q*256 + n] = acc;
  }
  __syncthreads();
  if (tid < 256) dxl[tid] = fmaxf(red[tid] + red[256+tid] + red[512+tid] + red[768+tid] + b2[tid], 0.f);
  __syncthreads();

  const int hl = tid & 31;      // lane within 32-lane virtual wave
  const int unit = tid >> 5;    // 0..31
  float dxv[8];
  #pragma unroll
  for (int j2 = 0; j2 < 8; ++j2) dxv[j2] = dxl[hl*8 + j2];
  const u16* kt = (const u16*)(ws + OFF_KT);
  const u16* vw = (const u16*)(ws + OFF_VW);
  const float* s0 = (const float*)(ws + OFF_S0);
  float m = -1e30f, S = 0.f, cx0 = 0.f, cx1 = 0.f, cx2 = 0.f, cx3 = 0.f, keep = 0.f;
  for (int i = 0; i < 8; ++i) {
    const int l = ch*256 + i*32 + unit;     // 32 consecutive rows across units
    const size_t row = (size_t)b*1024 + l;
    const u16x8 kv = *(const u16x8*)(kt + row*256 + hl*8);
    float sum = 0.f;
    #pragma unroll
    for (int j2 = 0; j2 < 8; ++j2) sum = fmaf(bf2f(kv[j2]), dxv[j2], sum);
    #pragma unroll
    for (int d = 1; d < 32; d <<= 1) sum += __shfl_xor(sum, d, 64);
    float sc = sum + s0[row];
    sc += (in_mask[row] == 0.f) ? -1e9f : 0.f;
    if (hl == i) keep = sc;
    const float mn = fmaxf(m, sc);
    const float cf = __expf(m - mn);
    const float e  = __expf(sc - mn);
    S = S*cf + e;
    cx0 *= cf; cx1 *= cf; cx2 *= cf; cx3 *= cf;
    m = mn;
    const u16x4 vv = *(const u16x4*)(vw + row*128 + hl*4);
    cx0 = fmaf(e, bf2f(vv[0]), cx0);
    cx1 = fmaf(e, bf2f(vv[1]), cx1);
    cx2 = fmaf(e, bf2f(vv[2]), cx2);
    cx3 = fmaf(e, bf2f(vv[3]), cx3);
  }
  if (hl < 8) ((float*)(ws + OFF_SC))[b*1024 + ch*256 + hl*32 + unit] = keep;
  mrg[unit*132 + 4 + hl*4 + 0] = cx0;
  mrg[unit*132 + 4 + hl*4 + 1] = cx1;
  mrg[unit*132 + 4 + hl*4 + 2] = cx2;
  mrg[unit*132 + 4 + hl*4 + 3] = cx3;
  if (hl == 0) { mrg[unit*132] = m; mrg[unit*132+1] = S; }
  __syncthreads();
  if (tid < 128) {   // merge 32 unit-partials -> chunk partial
    float mg = -1e30f;
    for (int u = 0; u < 32; ++u) mg = fmaxf(mg, mrg[u*132]);
    float Sg = 0.f, cx = 0.f;
    for (int u = 0; u < 32; ++u) {
      const float f = __expf(mrg[u*132] - mg);
      Sg = fmaf(mrg[u*132+1], f, Sg);
      cx = fmaf(f, mrg[u*132 + 4 + tid], cx);
    }
    float* part = (float*)(ws + OFF_PART);
    part[(b*4+ch)*130 + 2 + tid] = cx;
    if (tid == 0) { part[(b*4+ch)*130] = mg; part[(b*4+ch)*130+1] = Sg; }
  }
}

extern "C" void kernel_launch(void* const* d_in, const int* in_sizes, int n_in,
                              void* d_out, int out_size, void* d_ws, size_t ws_size,
                              hipStream_t stream)
{
  (void)in_sizes; (void)n_in; (void)out_size; (void)ws_size;
  const float* hid_r  = (const float*)d_in[0];
  const float* in_mask= (const float*)d_in[1];
  const float* init_in= (const float*)d_in[2];
  const float* h0     = (const float*)d_in[3];
  const float* c0     = (const float*)d_in[4];
  const float* W1     = (const float*)d_in[5];
  const float* b1     = (const float*)d_in[6];
  const float* Wih    = (const float*)d_in[7];
  const float* Whh    = (const float*)d_in[8];
  const float* bih    = (const float*)d_in[9];
  const float* bhh    = (const float*)d_in[10];
  const float* W2     = (const float*)d_in[11];
  const float* b2     = (const float*)d_in[12];
  const float* Wq     = (const float*)d_in[13];
  const float* bq     = (const float*)d_in[14];
  const float* Wk     = (const float*)d_in[15];
  const float* bk     = (const float*)d_in[16];
  const float* Wv     = (const float*)d_in[17];
  const float* bv     = (const float*)d_in[18];
  const float* W3     = (const float*)d_in[19];
  const float* b3     = (const float*)d_in[20];
  char* ws = (char*)d_ws;
  float* out = (float*)d_out;

  hipLaunchKernelGGL(kPrep, dim3(410), dim3(256), 0, stream, ws,
                     W1, Wih, Whh, W2, Wq, bq, Wk, bk, Wv, bv, W3, b3, bih, bhh, c0, h0);
  hipLaunchKernelGGL(kKTVW, dim3(2048), dim3(256), 0, stream, ws, hid_r);
  for (int s = 0; s < 1024; ++s) {
    hipLaunchKernelGGL(kA, dim3(256), dim3(512), 0, stream, ws, init_in, in_mask, b1, out, s);
    hipLaunchKernelGGL(kB, dim3(256), dim3(1024), 0, stream, ws, in_mask, b2, s);
  }
  hipLaunchKernelGGL(kA, dim3(256), dim3(512), 0, stream, ws, init_in, in_mask, b1, out, 1024);
}